// Round 3
// baseline (357.278 us; speedup 1.0000x reference)
//
#include <hip/hip_runtime.h>
#include <stdint.h>

// Problem constants
#define S_LEN 2048
#define DMODEL 1024
#define NHEAD 16
#define DKH 64
// M for all GEMMs = B*S = 4096, N = K = 1024

typedef __attribute__((ext_vector_type(8))) short short8;
typedef __attribute__((ext_vector_type(4))) short sv4;
typedef __attribute__((ext_vector_type(4))) float fv4;
typedef __attribute__((ext_vector_type(8))) __bf16 bf16x8;
typedef __attribute__((ext_vector_type(4))) float f32x4;

static __device__ __forceinline__ short f2bf(float f) {
  unsigned u = __builtin_bit_cast(unsigned, f);
  u = u + 0x7fffu + ((u >> 16) & 1u);   // RNE
  return (short)(u >> 16);
}

static __device__ __forceinline__ bf16x8 ldfrag(const void* p) {
  return __builtin_bit_cast(bf16x8, *(const short8*)p);
}

#define GLL16(gp, lp) __builtin_amdgcn_global_load_lds( \
    (const __attribute__((address_space(1))) unsigned int*)(const void*)(gp), \
    (__attribute__((address_space(3))) unsigned int*)(void*)(lp), 16, 0, 0)

// ---------------------------------------------------------------------------
// Kernel 1: f32 -> bf16 conversion of q,k,v and Wq,Wk,Wv,Wo
// ---------------------------------------------------------------------------
__global__ __launch_bounds__(256) void convert_all(
    const float* __restrict__ q, const float* __restrict__ k, const float* __restrict__ v,
    const float* __restrict__ wq, const float* __restrict__ wk, const float* __restrict__ wv,
    const float* __restrict__ wo,
    short* __restrict__ xb, short* __restrict__ wb, short* __restrict__ wob)
{
  const int total = 4194304;  // float4 groups: 3*(4M/4) + 4*(1M/4)
  for (int gid = blockIdx.x * blockDim.x + threadIdx.x; gid < total;
       gid += gridDim.x * blockDim.x) {
    const float* src; short* dst; int off;
    if (gid < 3145728) {
      int z = gid >> 20;
      off = (gid & 1048575) << 2;
      src = (z == 0) ? q : (z == 1) ? k : v;
      dst = xb + (size_t)z * 4194304;
    } else {
      int g = gid - 3145728;
      int z = g >> 18;
      off = (g & 262143) << 2;
      src = (z == 0) ? wq : (z == 1) ? wk : (z == 2) ? wv : wo;
      dst = (z < 3) ? (wb + (size_t)z * 1048576) : wob;
    }
    fv4 f = *(const fv4*)(src + off);
    sv4 o;
    o.x = f2bf(f.x); o.y = f2bf(f.y); o.z = f2bf(f.z); o.w = f2bf(f.w);
    *(sv4*)(dst + off) = o;
  }
}

// ---------------------------------------------------------------------------
// Kernel 2/4: C = A @ W^T + bias.  A:[4096][1024] bf16, W:[1024][1024] bf16
// (B^T layout).  128x128 tile, BK=64, 4 waves, 16x16x32 bf16 MFMA.
// LDS staged via global_load_lds with pre-swizzled source (byte ^= (row&7)<<4)
// so ds_read_b128 fragment reads are bank-conflict-free.
// ---------------------------------------------------------------------------
__global__ __launch_bounds__(256) void gemm_bt(
    const short* __restrict__ Abase, const short* __restrict__ Wbase,
    const float* __restrict__ bias0, const float* __restrict__ bias1,
    const float* __restrict__ bias2,
    short* __restrict__ Cbf, float* __restrict__ Cf)
{
  const int Kd = 1024, Nd = 1024, Md = 4096;
  const int z = blockIdx.z;
  const short* A = Abase + (size_t)z * Md * Kd;
  const short* W = Wbase + (size_t)z * Nd * Kd;
  const float* bias = (z == 0) ? bias0 : (z == 1) ? bias1 : bias2;

  __shared__ short8 As[1024];  // 128 rows x 64 cols bf16, swizzled (16KB)
  __shared__ short8 Bs[1024];

  const int tid = threadIdx.x;
  const int w = tid >> 6, lane = tid & 63;
  const int wr = w >> 1, wc = w & 1;
  const int lhi = lane >> 4, llo = lane & 15;
  const int m0 = blockIdx.y * 128, n0 = blockIdx.x * 128;

  const f32x4 zero = {0.f, 0.f, 0.f, 0.f};
  f32x4 acc[4][4];
#pragma unroll
  for (int i = 0; i < 4; ++i)
#pragma unroll
    for (int j = 0; j < 4; ++j) acc[i][j] = zero;

  for (int kt = 0; kt < Kd / 64; ++kt) {
    const int k0 = kt * 64;
    __syncthreads();
#pragma unroll
    for (int inst = 0; inst < 4; ++inst) {
      int ib = w * 4096 + inst * 1024 + lane * 16;       // byte slot in 16KB tile
      int row = ib >> 7;                                 // 128B per row
      int colb = (ib & 127) ^ ((row & 7) << 4);          // inverse swizzle source
      int col = colb >> 1;
      GLL16(A + (size_t)(m0 + row) * Kd + k0 + col,
            (char*)As + (w * 4096 + inst * 1024));
      GLL16(W + (size_t)(n0 + row) * Kd + k0 + col,
            (char*)Bs + (w * 4096 + inst * 1024));
    }
    __syncthreads();
#pragma unroll
    for (int kk = 0; kk < 2; ++kk) {
      bf16x8 af[4], bfm[4];
#pragma unroll
      for (int t = 0; t < 4; ++t) {
        int arow = wr * 64 + t * 16 + llo;
        int abyte = ((arow << 7) + ((kk * 32 + lhi * 8) << 1)) ^ ((arow & 7) << 4);
        af[t] = ldfrag((const char*)As + abyte);
        int brow = wc * 64 + t * 16 + llo;
        int bbyte = ((brow << 7) + ((kk * 32 + lhi * 8) << 1)) ^ ((brow & 7) << 4);
        bfm[t] = ldfrag((const char*)Bs + bbyte);
      }
#pragma unroll
      for (int i = 0; i < 4; ++i)
#pragma unroll
        for (int j = 0; j < 4; ++j)
          acc[i][j] = __builtin_amdgcn_mfma_f32_16x16x32_bf16(af[i], bfm[j], acc[i][j], 0, 0, 0);
    }
  }

  short* Co = Cbf ? (Cbf + (size_t)z * Md * Nd) : nullptr;
#pragma unroll
  for (int i = 0; i < 4; ++i) {
#pragma unroll
    for (int j = 0; j < 4; ++j) {
#pragma unroll
      for (int r = 0; r < 4; ++r) {
        int row = m0 + wr * 64 + i * 16 + lhi * 4 + r;
        int col = n0 + wc * 64 + j * 16 + llo;
        float vv = acc[i][j][r] + bias[col];
        if (Co) Co[(size_t)row * Nd + col] = f2bf(vv);
        else    Cf[(size_t)row * Nd + col] = vv;
      }
    }
  }
}

// ---------------------------------------------------------------------------
// Kernel 3: causal flash attention.
// Grid: x = S/64 q-tiles, y = B*H.  256 threads = 4 waves x 16 q-rows.
// K staged swizzled via global_load_lds; V staged transposed (pad 72);
// P routed through per-wave LDS.
// ---------------------------------------------------------------------------
__global__ __launch_bounds__(256) void attn_fwd(
    const short* __restrict__ Qp, const short* __restrict__ Kp,
    const short* __restrict__ Vp, short* __restrict__ Out)
{
  __shared__ short8 KsV[512];   // 64 x 64 bf16, swizzled (8KB)
  __shared__ short8 VtV[576];   // V^T: 64 d-rows x 72 (pad) bf16 (9216B)
  __shared__ short8 PsV[576];   // 4 waves x 16 x 72 bf16

  const int tid = threadIdx.x;
  const int w = tid >> 6, lane = tid & 63;
  const int lhi = lane >> 4, llo = lane & 15;
  const int qt = blockIdx.x;
  const int bh = blockIdx.y;
  const int b = bh >> 4, h = bh & 15;
  const int qbase = qt * 64;
  const size_t rowbase = (size_t)b * S_LEN;

  // Q fragments (held in registers for the whole block)
  bf16x8 qf[2];
  {
    const short* qrow = Qp + (rowbase + qbase + w * 16 + llo) * DMODEL + h * DKH;
    qf[0] = ldfrag(qrow + lhi * 8);
    qf[1] = ldfrag(qrow + 32 + lhi * 8);
  }

  const f32x4 zero = {0.f, 0.f, 0.f, 0.f};
  float m[4], l[4];
  f32x4 oacc[4];
#pragma unroll
  for (int r = 0; r < 4; ++r) { m[r] = -3.0e38f; l[r] = 0.f; }
#pragma unroll
  for (int dt = 0; dt < 4; ++dt) oacc[dt] = zero;

  short* Vt = (short*)VtV;
  short* Ps = (short*)PsV + w * 16 * 72;

  for (int kvt = 0; kvt <= qt; ++kvt) {
    const int kvbase = kvt * 64;
    __syncthreads();   // prior tile's P/V reads done before restage
    // stage K (swizzled, async direct-to-LDS)
#pragma unroll
    for (int inst = 0; inst < 2; ++inst) {
      int ib = w * 2048 + inst * 1024 + lane * 16;
      int row = ib >> 7;
      int colb = (ib & 127) ^ ((row & 7) << 4);
      GLL16(Kp + (rowbase + kvbase + row) * DMODEL + h * DKH + (colb >> 1),
            (char*)KsV + (w * 2048 + inst * 1024));
    }
    // stage V transposed: thread t -> kv = t&63, d-block = t>>6
    {
      int kv = tid & 63, dgrp = tid >> 6;
      const short* g = Vp + (rowbase + kvbase + kv) * DMODEL + h * DKH + dgrp * 16;
      short8 v0 = *(const short8*)g;
      short8 v1 = *(const short8*)(g + 8);
#pragma unroll
      for (int j = 0; j < 8; ++j) Vt[(dgrp * 16 + j) * 72 + kv] = v0[j];
#pragma unroll
      for (int j = 0; j < 8; ++j) Vt[(dgrp * 16 + 8 + j) * 72 + kv] = v1[j];
    }
    __syncthreads();

    // QK^T for this wave's 16 q-rows x 64 kv
    f32x4 sc[4];
#pragma unroll
    for (int t = 0; t < 4; ++t) sc[t] = zero;
#pragma unroll
    for (int kk = 0; kk < 2; ++kk) {
#pragma unroll
      for (int t = 0; t < 4; ++t) {
        int krow = t * 16 + llo;
        int kbyte = ((krow << 7) + ((kk * 32 + lhi * 8) << 1)) ^ ((krow & 7) << 4);
        bf16x8 kf = ldfrag((const char*)KsV + kbyte);
        sc[t] = __builtin_amdgcn_mfma_f32_16x16x32_bf16(qf[kk], kf, sc[t], 0, 0, 0);
      }
    }

    // mask + online softmax (row = lhi*4 + r, col = llo within 16-col tile t)
    const bool diag = (kvt == qt);
    float p[4][4];
#pragma unroll
    for (int r = 0; r < 4; ++r) {
      float tm = -3.0e38f;
#pragma unroll
      for (int t = 0; t < 4; ++t) {
        float s = sc[t][r];
        if (diag) {
          int kg = kvbase + t * 16 + llo;
          int qg = qbase + w * 16 + lhi * 4 + r;
          if (kg > qg) s = -3.0e38f;
        }
        p[t][r] = s;
        tm = fmaxf(tm, s);
      }
      tm = fmaxf(tm, __shfl_xor(tm, 1));
      tm = fmaxf(tm, __shfl_xor(tm, 2));
      tm = fmaxf(tm, __shfl_xor(tm, 4));
      tm = fmaxf(tm, __shfl_xor(tm, 8));
      float mnew = fmaxf(m[r], tm);
      float alpha = __expf(0.125f * (m[r] - mnew));
      m[r] = mnew;
      float rs = 0.f;
#pragma unroll
      for (int t = 0; t < 4; ++t) {
        float pv = __expf(0.125f * (p[t][r] - mnew));
        p[t][r] = pv;
        rs += pv;
      }
      rs += __shfl_xor(rs, 1);
      rs += __shfl_xor(rs, 2);
      rs += __shfl_xor(rs, 4);
      rs += __shfl_xor(rs, 8);
      l[r] = l[r] * alpha + rs;
#pragma unroll
      for (int dt = 0; dt < 4; ++dt) oacc[dt][r] = oacc[dt][r] * alpha;
#pragma unroll
      for (int t = 0; t < 4; ++t)
        Ps[(lhi * 4 + r) * 72 + t * 16 + llo] = f2bf(p[t][r]);
    }
    __syncthreads();   // P writes visible (cross-lane via LDS)

    // PV: oacc[q][d] += P[q][kv] @ V[kv][d]
#pragma unroll
    for (int kk = 0; kk < 2; ++kk) {
      bf16x8 pa = ldfrag(Ps + llo * 72 + kk * 32 + lhi * 8);
#pragma unroll
      for (int dt = 0; dt < 4; ++dt) {
        bf16x8 vf = ldfrag(Vt + (dt * 16 + llo) * 72 + kk * 32 + lhi * 8);
        oacc[dt] = __builtin_amdgcn_mfma_f32_16x16x32_bf16(pa, vf, oacc[dt], 0, 0, 0);
      }
    }
  }

  // epilogue: normalize and store combined-head layout [B*S][D]
#pragma unroll
  for (int dt = 0; dt < 4; ++dt) {
#pragma unroll
    for (int r = 0; r < 4; ++r) {
      float vv = oacc[dt][r] / l[r];
      int row = qbase + w * 16 + lhi * 4 + r;
      int col = h * DKH + dt * 16 + llo;
      Out[(rowbase + row) * DMODEL + col] = f2bf(vv);
    }
  }
}

// ---------------------------------------------------------------------------
extern "C" void kernel_launch(void* const* d_in, const int* in_sizes, int n_in,
                              void* d_out, int out_size, void* d_ws, size_t ws_size,
                              hipStream_t stream) {
  (void)in_sizes; (void)n_in; (void)out_size; (void)ws_size;
  const float* q  = (const float*)d_in[0];
  const float* k  = (const float*)d_in[1];
  const float* v  = (const float*)d_in[2];
  // d_in[3] = causal mask (structure known, ignored)
  const float* Wq = (const float*)d_in[4];
  const float* bq = (const float*)d_in[5];
  const float* Wk = (const float*)d_in[6];
  const float* bk = (const float*)d_in[7];
  const float* Wv = (const float*)d_in[8];
  const float* bv = (const float*)d_in[9];
  const float* Wo = (const float*)d_in[10];
  const float* bo = (const float*)d_in[11];
  float* out = (float*)d_out;

  // workspace layout (bf16/short units), ~59MB total
  short* xb   = (short*)d_ws;              // 3 * 4194304 (q,k,v bf16)
  short* wb   = xb + 3ull * 4194304;       // 3 * 1048576 (Wq,Wk,Wv bf16)
  short* wob  = wb + 3ull * 1048576;       // 1048576    (Wo bf16)
  short* proj = wob + 1048576;             // 3 * 4194304 (Q,K,V projected)
  short* attno = xb;                       // reuse xb (free after projections)

  convert_all<<<dim3(2048), dim3(256), 0, stream>>>(q, k, v, Wq, Wk, Wv, Wo, xb, wb, wob);
  gemm_bt<<<dim3(8, 32, 3), dim3(256), 0, stream>>>(xb, wb, bq, bk, bv, proj, nullptr);
  attn_fwd<<<dim3(32, 32), dim3(256), 0, stream>>>(proj, proj + 4194304ull,
                                                   proj + 2ull * 4194304, attno);
  gemm_bt<<<dim3(8, 32, 1), dim3(256), 0, stream>>>(attno, wob, bo, bo, bo, nullptr, out);
}

// Round 4
// 281.110 us; speedup vs baseline: 1.2710x; 1.2710x over previous
//
#include <hip/hip_runtime.h>
#include <stdint.h>

// Problem constants
#define S_LEN 2048
#define DMODEL 1024
#define NHEAD 16
#define DKH 64
// M for all GEMMs = B*S = 4096, N = K = 1024

typedef __attribute__((ext_vector_type(8))) short short8;
typedef __attribute__((ext_vector_type(4))) short sv4;
typedef __attribute__((ext_vector_type(4))) float fv4;
typedef __attribute__((ext_vector_type(8))) __bf16 bf16x8;
typedef __attribute__((ext_vector_type(4))) float f32x4;

// 0.125 (1/sqrt(DK)) * log2(e): folded into Wq/bq so softmax can use native exp2
#define QSCALE 0.18033688011112042f

static __device__ __forceinline__ short f2bf(float f) {
  unsigned u = __builtin_bit_cast(unsigned, f);
  u = u + 0x7fffu + ((u >> 16) & 1u);   // RNE
  return (short)(u >> 16);
}

static __device__ __forceinline__ bf16x8 ldfrag(const void* p) {
  return __builtin_bit_cast(bf16x8, *(const short8*)p);
}

#define GLL16(gp, lp) __builtin_amdgcn_global_load_lds( \
    (const __attribute__((address_space(1))) unsigned int*)(const void*)(gp), \
    (__attribute__((address_space(3))) unsigned int*)(void*)(lp), 16, 0, 0)

#define WAIT_VMCNT0() asm volatile("s_waitcnt vmcnt(0)" ::: "memory")
#define WAIT_LGKM0()  asm volatile("s_waitcnt lgkmcnt(0)" ::: "memory")

// ---------------------------------------------------------------------------
// Kernel 1: f32 -> bf16 conversion of q,k,v and Wq,Wk,Wv,Wo.
// Wq is pre-scaled by QSCALE (softmax then uses exp2 with no per-elem scale).
// ---------------------------------------------------------------------------
__global__ __launch_bounds__(256) void convert_all(
    const float* __restrict__ q, const float* __restrict__ k, const float* __restrict__ v,
    const float* __restrict__ wq, const float* __restrict__ wk, const float* __restrict__ wv,
    const float* __restrict__ wo,
    short* __restrict__ xb, short* __restrict__ wb, short* __restrict__ wob)
{
  const int total = 4194304;  // float4 groups: 3*(4M/4) + 4*(1M/4)
  for (int gid = blockIdx.x * blockDim.x + threadIdx.x; gid < total;
       gid += gridDim.x * blockDim.x) {
    const float* src; short* dst; int off; float scl = 1.0f;
    if (gid < 3145728) {
      int z = gid >> 20;
      off = (gid & 1048575) << 2;
      src = (z == 0) ? q : (z == 1) ? k : v;
      dst = xb + (size_t)z * 4194304;
    } else {
      int g = gid - 3145728;
      int z = g >> 18;
      off = (g & 262143) << 2;
      src = (z == 0) ? wq : (z == 1) ? wk : (z == 2) ? wv : wo;
      dst = (z < 3) ? (wb + (size_t)z * 1048576) : wob;
      if (z == 0) scl = QSCALE;
    }
    fv4 f = *(const fv4*)(src + off);
    sv4 o;
    o.x = f2bf(f.x * scl); o.y = f2bf(f.y * scl);
    o.z = f2bf(f.z * scl); o.w = f2bf(f.w * scl);
    *(sv4*)(dst + off) = o;
  }
}

// ---------------------------------------------------------------------------
// Kernel 2/4: C = A @ W^T + bias.  (m97 structure, unchanged this round)
// bscl0: bias scale applied to batch z==0 only (QSCALE for the Q projection).
// ---------------------------------------------------------------------------
__global__ __launch_bounds__(256) void gemm_bt(
    const short* __restrict__ Abase, const short* __restrict__ Wbase,
    const float* __restrict__ bias0, const float* __restrict__ bias1,
    const float* __restrict__ bias2, float bscl0,
    short* __restrict__ Cbf, float* __restrict__ Cf)
{
  const int Kd = 1024, Nd = 1024, Md = 4096;
  const int z = blockIdx.z;
  const short* A = Abase + (size_t)z * Md * Kd;
  const short* W = Wbase + (size_t)z * Nd * Kd;
  const float* bias = (z == 0) ? bias0 : (z == 1) ? bias1 : bias2;
  const float bscl = (z == 0) ? bscl0 : 1.0f;

  __shared__ short8 As[1024];  // 128 rows x 64 cols bf16, swizzled (16KB)
  __shared__ short8 Bs[1024];

  const int tid = threadIdx.x;
  const int w = tid >> 6, lane = tid & 63;
  const int wr = w >> 1, wc = w & 1;
  const int lhi = lane >> 4, llo = lane & 15;
  const int m0 = blockIdx.y * 128, n0 = blockIdx.x * 128;

  const f32x4 zero = {0.f, 0.f, 0.f, 0.f};
  f32x4 acc[4][4];
#pragma unroll
  for (int i = 0; i < 4; ++i)
#pragma unroll
    for (int j = 0; j < 4; ++j) acc[i][j] = zero;

  for (int kt = 0; kt < Kd / 64; ++kt) {
    const int k0 = kt * 64;
    __syncthreads();
#pragma unroll
    for (int inst = 0; inst < 4; ++inst) {
      int ib = w * 4096 + inst * 1024 + lane * 16;       // byte slot in 16KB tile
      int row = ib >> 7;                                 // 128B per row
      int colb = (ib & 127) ^ ((row & 7) << 4);          // inverse swizzle source
      int col = colb >> 1;
      GLL16(A + (size_t)(m0 + row) * Kd + k0 + col,
            (char*)As + (w * 4096 + inst * 1024));
      GLL16(W + (size_t)(n0 + row) * Kd + k0 + col,
            (char*)Bs + (w * 4096 + inst * 1024));
    }
    __syncthreads();
#pragma unroll
    for (int kk = 0; kk < 2; ++kk) {
      bf16x8 af[4], bfm[4];
#pragma unroll
      for (int t = 0; t < 4; ++t) {
        int arow = wr * 64 + t * 16 + llo;
        int abyte = ((arow << 7) + ((kk * 32 + lhi * 8) << 1)) ^ ((arow & 7) << 4);
        af[t] = ldfrag((const char*)As + abyte);
        int brow = wc * 64 + t * 16 + llo;
        int bbyte = ((brow << 7) + ((kk * 32 + lhi * 8) << 1)) ^ ((brow & 7) << 4);
        bfm[t] = ldfrag((const char*)Bs + bbyte);
      }
#pragma unroll
      for (int i = 0; i < 4; ++i)
#pragma unroll
        for (int j = 0; j < 4; ++j)
          acc[i][j] = __builtin_amdgcn_mfma_f32_16x16x32_bf16(af[i], bfm[j], acc[i][j], 0, 0, 0);
    }
  }

  short* Co = Cbf ? (Cbf + (size_t)z * Md * Nd) : nullptr;
#pragma unroll
  for (int i = 0; i < 4; ++i) {
#pragma unroll
    for (int j = 0; j < 4; ++j) {
#pragma unroll
      for (int r = 0; r < 4; ++r) {
        int row = m0 + wr * 64 + i * 16 + lhi * 4 + r;
        int col = n0 + wc * 64 + j * 16 + llo;
        float vv = acc[i][j][r] + bias[col] * bscl;
        if (Co) Co[(size_t)row * Nd + col] = f2bf(vv);
        else    Cf[(size_t)row * Nd + col] = vv;
      }
    }
  }
}

// ---------------------------------------------------------------------------
// Kernel 3: causal flash attention, pipelined.
// Grid: x in [0,16) -> block handles q-tiles {x, 31-x} (33 kv-tiles each:
// perfect balance).  y = B*H.  256 threads = 4 waves x 16 q-rows.
// Double-buffered K (GLL, swizzled) and V^T (reg 4x4 transpose, pad 72).
// Per tile: vmcnt(0); V^T write; issue next-tile loads; lgkm+barrier(B1);
// QK; softmax; PV; barrier(B2).  No __syncthreads in main loop, so the
// next tile's HBM loads stay in flight across the whole compute phase.
// ---------------------------------------------------------------------------
__global__ __launch_bounds__(256) void attn_fwd(
    const short* __restrict__ Qp, const short* __restrict__ Kp,
    const short* __restrict__ Vp, short* __restrict__ Out)
{
  __shared__ short8 Ks[2][512];      // 2 x 64x64 bf16, swizzled (16KB)
  __shared__ short  Vt[2][64 * 72];  // 2 x V^T 64 d-rows x 72-pad (18KB)
  __shared__ short  PsA[4][16 * 72]; // per-wave P (9KB)

  const int tid = threadIdx.x;
  const int w = tid >> 6, lane = tid & 63;
  const int lhi = lane >> 4, llo = lane & 15;
  const int x = blockIdx.x;
  const int bh = blockIdx.y;
  const int b = bh >> 4, h = bh & 15;
  const size_t rowbase = (size_t)b * S_LEN;
  const short* Kbase = Kp + rowbase * DMODEL + h * DKH;
  const short* Vbase = Vp + rowbase * DMODEL + h * DKH;

  const int dg = tid & 15, kvg = tid >> 4;   // V staging: 4x4 block (d0=dg*4, kv0=kvg*4)
  short* Ps = PsA[w];
  const f32x4 zero = {0.f, 0.f, 0.f, 0.f};

  for (int seq = 0; seq < 2; ++seq) {
    const int qt = (seq == 0) ? x : (31 - x);
    const int nt = qt + 1;
    const int qbase = qt * 64;

    __syncthreads();   // seq boundary: full drain before buffer reuse

    // Q fragments
    bf16x8 qf[2];
    {
      const short* qrow = Qp + (rowbase + qbase + w * 16 + llo) * DMODEL + h * DKH;
      qf[0] = ldfrag(qrow + lhi * 8);
      qf[1] = ldfrag(qrow + 32 + lhi * 8);
    }

    float mr[4], lr[4];
    f32x4 oacc[4];
#pragma unroll
    for (int r = 0; r < 4; ++r) { mr[r] = -3.0e38f; lr[r] = 0.f; }
#pragma unroll
    for (int dt = 0; dt < 4; ++dt) oacc[dt] = zero;

    // prologue: stage tile 0
#pragma unroll
    for (int inst = 0; inst < 2; ++inst) {
      int ib = w * 2048 + inst * 1024 + lane * 16;
      int row = ib >> 7;
      int colb = (ib & 127) ^ ((row & 7) << 4);
      GLL16(Kbase + (size_t)row * DMODEL + (colb >> 1),
            (char*)&Ks[0][0] + (w * 2048 + inst * 1024));
    }
    sv4 vr0, vr1, vr2, vr3;
    vr0 = *(const sv4*)(Vbase + (size_t)(kvg * 4 + 0) * DMODEL + dg * 4);
    vr1 = *(const sv4*)(Vbase + (size_t)(kvg * 4 + 1) * DMODEL + dg * 4);
    vr2 = *(const sv4*)(Vbase + (size_t)(kvg * 4 + 2) * DMODEL + dg * 4);
    vr3 = *(const sv4*)(Vbase + (size_t)(kvg * 4 + 3) * DMODEL + dg * 4);

    for (int t = 0; t < nt; ++t) {
      const int cur = t & 1, nxt = cur ^ 1;
      const int kvbase = t * 64;

      WAIT_VMCNT0();   // own K-GLL(t) + V-regs(t) complete
      // write V^T(t): 4x4 register transpose -> 4 x ds_write_b64
#pragma unroll
      for (int d = 0; d < 4; ++d) {
        sv4 wv;
        wv.x = vr0[d]; wv.y = vr1[d]; wv.z = vr2[d]; wv.w = vr3[d];
        *(sv4*)&Vt[cur][(dg * 4 + d) * 72 + kvg * 4] = wv;
      }
      // issue next-tile loads (stay in flight across compute)
      if (t + 1 < nt) {
        const int nb = kvbase + 64;
#pragma unroll
        for (int inst = 0; inst < 2; ++inst) {
          int ib = w * 2048 + inst * 1024 + lane * 16;
          int row = ib >> 7;
          int colb = (ib & 127) ^ ((row & 7) << 4);
          GLL16(Kbase + (size_t)(nb + row) * DMODEL + (colb >> 1),
                (char*)&Ks[nxt][0] + (w * 2048 + inst * 1024));
        }
        vr0 = *(const sv4*)(Vbase + (size_t)(nb + kvg * 4 + 0) * DMODEL + dg * 4);
        vr1 = *(const sv4*)(Vbase + (size_t)(nb + kvg * 4 + 1) * DMODEL + dg * 4);
        vr2 = *(const sv4*)(Vbase + (size_t)(nb + kvg * 4 + 2) * DMODEL + dg * 4);
        vr3 = *(const sv4*)(Vbase + (size_t)(nb + kvg * 4 + 3) * DMODEL + dg * 4);
      }
      WAIT_LGKM0();
      __builtin_amdgcn_s_barrier();   // B1: all staging for tile t visible

      // QK^T
      f32x4 sc[4];
#pragma unroll
      for (int tt = 0; tt < 4; ++tt) sc[tt] = zero;
      __builtin_amdgcn_s_setprio(1);
#pragma unroll
      for (int kk = 0; kk < 2; ++kk) {
#pragma unroll
        for (int tt = 0; tt < 4; ++tt) {
          int krow = tt * 16 + llo;
          int kbyte = ((krow << 7) + ((kk * 32 + lhi * 8) << 1)) ^ ((krow & 7) << 4);
          bf16x8 kf = ldfrag((const char*)&Ks[cur][0] + kbyte);
          sc[tt] = __builtin_amdgcn_mfma_f32_16x16x32_bf16(qf[kk], kf, sc[tt], 0, 0, 0);
        }
      }
      __builtin_amdgcn_s_setprio(0);

      // mask + online softmax (exp2 domain; scores pre-scaled via Wq)
      const bool diag = (t == qt);
      float p[4][4];
#pragma unroll
      for (int r = 0; r < 4; ++r) {
        float tm = -3.0e38f;
#pragma unroll
        for (int tt = 0; tt < 4; ++tt) {
          float s = sc[tt][r];
          if (diag) {
            int kg = kvbase + tt * 16 + llo;
            int qg = qbase + w * 16 + lhi * 4 + r;
            if (kg > qg) s = -3.0e38f;
          }
          p[tt][r] = s;
          tm = fmaxf(tm, s);
        }
        tm = fmaxf(tm, __shfl_xor(tm, 1));
        tm = fmaxf(tm, __shfl_xor(tm, 2));
        tm = fmaxf(tm, __shfl_xor(tm, 4));
        tm = fmaxf(tm, __shfl_xor(tm, 8));
        float mnew = fmaxf(mr[r], tm);
        float alpha = __builtin_amdgcn_exp2f(mr[r] - mnew);
        mr[r] = mnew;
        float rs = 0.f;
#pragma unroll
        for (int tt = 0; tt < 4; ++tt) {
          float pv = __builtin_amdgcn_exp2f(p[tt][r] - mnew);
          p[tt][r] = pv;
          rs += pv;
        }
        rs += __shfl_xor(rs, 1);
        rs += __shfl_xor(rs, 2);
        rs += __shfl_xor(rs, 4);
        rs += __shfl_xor(rs, 8);
        lr[r] = lr[r] * alpha + rs;
#pragma unroll
        for (int dt = 0; dt < 4; ++dt) oacc[dt][r] = oacc[dt][r] * alpha;
#pragma unroll
        for (int tt = 0; tt < 4; ++tt)
          Ps[(lhi * 4 + r) * 72 + tt * 16 + llo] = f2bf(p[tt][r]);
      }
      // P is per-wave: wave-internal LDS ordering handled by compiler waits.

      // PV
      __builtin_amdgcn_s_setprio(1);
#pragma unroll
      for (int kk = 0; kk < 2; ++kk) {
        bf16x8 pa = ldfrag(Ps + llo * 72 + kk * 32 + lhi * 8);
#pragma unroll
        for (int dt = 0; dt < 4; ++dt) {
          bf16x8 vf = ldfrag(&Vt[cur][(dt * 16 + llo) * 72 + kk * 32 + lhi * 8]);
          oacc[dt] = __builtin_amdgcn_mfma_f32_16x16x32_bf16(pa, vf, oacc[dt], 0, 0, 0);
        }
      }
      __builtin_amdgcn_s_setprio(0);
      __builtin_amdgcn_s_barrier();   // B2: reads of buf[cur] done before reuse
    }

    // epilogue: normalize and store combined-head layout [B*S][D]
#pragma unroll
    for (int dt = 0; dt < 4; ++dt) {
#pragma unroll
      for (int r = 0; r < 4; ++r) {
        float vv = oacc[dt][r] / lr[r];
        int row = qbase + w * 16 + lhi * 4 + r;
        int col = h * DKH + dt * 16 + llo;
        Out[(rowbase + row) * DMODEL + col] = f2bf(vv);
      }
    }
  }
}

// ---------------------------------------------------------------------------
extern "C" void kernel_launch(void* const* d_in, const int* in_sizes, int n_in,
                              void* d_out, int out_size, void* d_ws, size_t ws_size,
                              hipStream_t stream) {
  (void)in_sizes; (void)n_in; (void)out_size; (void)ws_size;
  const float* q  = (const float*)d_in[0];
  const float* k  = (const float*)d_in[1];
  const float* v  = (const float*)d_in[2];
  // d_in[3] = causal mask (structure known, ignored)
  const float* Wq = (const float*)d_in[4];
  const float* bq = (const float*)d_in[5];
  const float* Wk = (const float*)d_in[6];
  const float* bk = (const float*)d_in[7];
  const float* Wv = (const float*)d_in[8];
  const float* bv = (const float*)d_in[9];
  const float* Wo = (const float*)d_in[10];
  const float* bo = (const float*)d_in[11];
  float* out = (float*)d_out;

  // workspace layout (bf16/short units), ~59MB total
  short* xb   = (short*)d_ws;              // 3 * 4194304 (q,k,v bf16)
  short* wb   = xb + 3ull * 4194304;       // 3 * 1048576 (Wq,Wk,Wv bf16; Wq pre-scaled)
  short* wob  = wb + 3ull * 1048576;       // 1048576    (Wo bf16)
  short* proj = wob + 1048576;             // 3 * 4194304 (Q,K,V projected)
  short* attno = xb;                       // reuse xb (free after projections)

  convert_all<<<dim3(2048), dim3(256), 0, stream>>>(q, k, v, Wq, Wk, Wv, Wo, xb, wb, wob);
  gemm_bt<<<dim3(8, 32, 3), dim3(256), 0, stream>>>(xb, wb, bq, bk, bv, QSCALE, proj, nullptr);
  attn_fwd<<<dim3(16, 32), dim3(256), 0, stream>>>(proj, proj + 4194304ull,
                                                   proj + 2ull * 4194304, attno);
  gemm_bt<<<dim3(8, 32, 1), dim3(256), 0, stream>>>(attno, wob, bo, bo, bo, 1.0f, nullptr, out);
}